// Round 3
// baseline (502.433 us; speedup 1.0000x reference)
//
#include <hip/hip_runtime.h>
#include <hip/hip_bf16.h>
#include <cstdint>

// MFVI second-order CRF, B=32 S=1024 T=256 W=2 ITER=3.
// Round 8: ONE fused iteration kernel (dispatch count 4 -> 2).
//  Theory: per-dispatch fixed cost ~45us dominates (rounds 5/6/7 all ~290us
//  regardless of kernel content; "coop replay cost 188us" corroborates).
//  P stays resident in LDS across all 3 iterations; only 4 halo rows per
//  tile per iteration (2KB) are exchanged via global memory with
//  device-scope release/acquire flags (neighbor-only pipelined sync).
//  Residency: grid 512 = 2 blocks/CU x 256 CUs exactly (LDS 69.6KB -> 2/CU,
//  launch_bounds(512,4) -> <=128 VGPR). Deps only on previous-iteration
//  neighbor flags -> no cycles, no deadlock.
//
// ws: WcTt bf16 [32][1024]x16B @0 (512KB) | Halo bf16 [2][512][4][256] @1MB
//     | Flags int[512] @4MB

typedef __attribute__((ext_vector_type(4))) float f32x4;
typedef __attribute__((ext_vector_type(8))) short bf16x8;

__device__ __forceinline__ void load_lds16(const void* g, void* l) {
    __builtin_amdgcn_global_load_lds(
        (const __attribute__((address_space(1))) void*)g,
        (__attribute__((address_space(3))) void*)l, 16, 0, 0);
}

// ---------------- prep: tiled+pre-swizzled WcT build + flag zeroing ---------
// WcTt chunk (p, sl): sl = n*4 + cs holds global k-chunk gk = p*4 +
// (cs ^ ((n>>1)&3)) of logical WcT row n (matches K-loop B-read involution).
__global__ __launch_bounds__(256) void prep_wct(
    const float* __restrict__ trans,
    __hip_bfloat16* __restrict__ WcTt, int* __restrict__ Flags)
{
    int idx = blockIdx.x * 256 + threadIdx.x;
    if (blockIdx.x == 0) {
        Flags[threadIdx.x] = 0;
        Flags[256 + threadIdx.x] = 0;
    }
    int p = idx >> 10, sl = idx & 1023;
    int n = sl >> 2, cs = sl & 3;
    int gk = p * 4 + (cs ^ ((n >> 1) & 3));
    union { bf16x8 v; __hip_bfloat16 h[8]; } o;
    #pragma unroll
    for (int e = 0; e < 8; ++e) {
        int k = gk * 8 + e;
        int r = k >> 8, kk = k & 255;
        float v;
        if (r == 0)      v = trans[kk * 256 + n];
        else if (r == 1) v = trans[65536 + kk * 256 + n];
        else if (r == 2) v = trans[n * 256 + kk];
        else             v = trans[65536 + n * 256 + kk];
        o.h[e] = __float2bfloat16(v);
    }
    ((bf16x8*)WcTt)[idx] = o.v;
}

// ---------------- fused 3-iteration kernel ----------------------------------
__global__ __launch_bounds__(512, 4) void mfvi_fused(
    const __hip_bfloat16* __restrict__ WcTt,  // [32][1024] x 16B tiles
    const float* __restrict__ unary, const int* __restrict__ lengths,
    const float* __restrict__ startT, const float* __restrict__ endT,
    __hip_bfloat16* Halo,                     // [2][512][4][256]
    int* Flags,                               // [512]
    float* __restrict__ out)
{
    __shared__ __hip_bfloat16 Ps[68 * 256];       // 34816 B
    __shared__ __hip_bfloat16 Bs[2 * 256 * 32];   // 2 x 16384 B
    __shared__ float redA[256];                   // [nslice][row]
    __shared__ float redB[256];

    int tid = threadIdx.x;
    int lane = tid & 63, w = tid >> 6;
    int cn = lane & 15, quad = lane >> 4;
    int wm = (w >> 2) * 32, wn = (w & 3) * 64;
    int nslice = w & 3;
    // XCD swizzle: each batch's 16 tiles share an XCD (bijective on [0,512))
    int tile = ((blockIdx.x & 7) << 6) | (blockIdx.x >> 3);
    int b = tile >> 4, s0 = (tile & 15) << 6;
    int len = lengths[b];
    int tpos = tile & 15;

    // Bs stage for K-step p into buffer bb: linear coalesced 16KB DMA.
    auto stageB = [&](int bb, int p) {
        #pragma unroll
        for (int c = 0; c < 2; ++c) {
            int sl = c * 512 + tid;
            load_lds16((const char*)WcTt + p * 16384 + sl * 16,
                       (char*)Bs + bb * 16384 + sl * 16);
        }
    };

    #pragma unroll 1
    for (int it = 1; it <= 3; ++it) {
        if (it == 1) {
            // ---- prologue: P_1 row r (padded 0..67) = softmax(masked unary
            // row s0+r-2), bf16 into swizzled Ps. Halo rows computed locally.
            for (int q = 0; q < 9; ++q) {
                int r = w + q * 8;
                if (r >= 68) break;
                int s = s0 + r - 2;
                int ch = lane >> 1;
                int slot = (ch & ~7) | ((ch ^ r) & 7);
                char* dst = (char*)Ps + r * 512 + slot * 16 + (lane & 1) * 8;
                if (s >= 0 && s < 1024) {
                    float mval = (s < len) ? 1.f : 0.f;
                    float4 x = *((const float4*)(unary + ((size_t)((b << 10) + s)) * 256 + lane * 4));
                    x.x *= mval; x.y *= mval; x.z *= mval; x.w *= mval;
                    float mx = fmaxf(fmaxf(x.x, x.y), fmaxf(x.z, x.w));
                    #pragma unroll
                    for (int o = 32; o; o >>= 1) mx = fmaxf(mx, __shfl_xor(mx, o));
                    float ea = __expf(x.x - mx), eb = __expf(x.y - mx);
                    float ec = __expf(x.z - mx), ed = __expf(x.w - mx);
                    float sum = ea + eb + ec + ed;
                    #pragma unroll
                    for (int o = 32; o; o >>= 1) sum += __shfl_xor(sum, o);
                    float inv = 1.0f / sum;
                    union { ushort4 u; __hip_bfloat16 h[4]; } o4;
                    o4.h[0] = __float2bfloat16(ea * inv);
                    o4.h[1] = __float2bfloat16(eb * inv);
                    o4.h[2] = __float2bfloat16(ec * inv);
                    o4.h[3] = __float2bfloat16(ed * inv);
                    *((ushort4*)dst) = o4.u;
                } else {
                    ushort4 z = {0, 0, 0, 0};
                    *((ushort4*)dst) = z;
                }
            }
        } else {
            // ---- neighbor sync: wait for prev-iter halo, then load 4 rows.
            if (tid == 0) {
                if (tpos != 0)
                    while (atomicAdd(Flags + tile - 1, 0) < it - 1)
                        __builtin_amdgcn_s_sleep(1);
                if (tpos != 15)
                    while (atomicAdd(Flags + tile + 1, 0) < it - 1)
                        __builtin_amdgcn_s_sleep(1);
            }
            __syncthreads();
            __threadfence();        // acquire: invalidate L1/L2 before reads
            if (tid < 128) {
                int r_idx = tid >> 5, ch = tid & 31;
                int pr = (r_idx < 2) ? r_idx : 64 + r_idx;         // 0,1,66,67
                bool left = (r_idx < 2);
                bool valid = left ? (tpos != 0) : (tpos != 15);
                int nbr = left ? tile - 1 : tile + 1;
                int src_row = left ? 2 + r_idx : r_idx - 2;
                int gch = (ch & ~7) | ((ch ^ pr) & 7);
                bf16x8 v = {};
                if (valid)
                    v = *(const bf16x8*)(Halo +
                        ((((size_t)(it - 2) * 512 + nbr) * 4 + src_row) * 256) + gch * 8);
                *(bf16x8*)((char*)Ps + (pr * 32 + ch) * 16) = v;
            }
        }

        stageB(0, 0);
        __syncthreads();          // drains Ps writes + Bs[0] DMA

        f32x4 acc[2][4] = {};

        // ---- K-loop: 32 steps of K=32, one barrier/step, Bs prefetched.
        #pragma unroll 2
        for (int p = 0; p < 32; ++p) {
            if (p < 31) stageB((p + 1) & 1, p + 1);

            int region = p >> 3;
            int delta = (region == 0) ? -1 : (region == 1) ? -2
                      : (region == 2) ?  1 : 2;
            int gcb = (p & 7) * 4 + quad;

            bf16x8 af[2], bfv[4];
            #pragma unroll
            for (int i = 0; i < 2; ++i) {
                int r = wm + (i << 4) + cn + delta + 2;     // 0..67
                int slot = (gcb & ~7) | ((gcb ^ r) & 7);
                af[i] = *(const bf16x8*)((const char*)Ps + r * 512 + slot * 16);
            }
            #pragma unroll
            for (int j = 0; j < 4; ++j) {
                int n = wn + (j << 4) + cn;
                int cs = quad ^ ((n >> 1) & 3);
                bfv[j] = *(const bf16x8*)((const char*)Bs + (p & 1) * 16384 + n * 64 + cs * 16);
            }
            #pragma unroll
            for (int i = 0; i < 2; ++i)
                #pragma unroll
                for (int j = 0; j < 4; ++j)
                    acc[i][j] = __builtin_amdgcn_mfma_f32_16x16x32_bf16(
                        af[i], bfv[j], acc[i][j], 0, 0, 0);

            __syncthreads();
        }

        // ---- boundary + unary + mask. C/D: col=lane&15, row=quad*4+reg
        #pragma unroll
        for (int i = 0; i < 2; ++i)
            #pragma unroll
            for (int j = 0; j < 4; ++j) {
                int n = wn + (j << 4) + cn;
                #pragma unroll
                for (int r = 0; r < 4; ++r) {
                    int s = s0 + wm + (i << 4) + (quad << 2) + r;
                    float x = acc[i][j][r];
                    if (s == 0)       x += startT[n];
                    if (s == 1)       x += startT[256 + n];
                    if (s == len - 1) x += endT[n];
                    if (s == len - 2) x += endT[256 + n];
                    long idx = ((long)((b << 10) + s)) * 256 + n;
                    x += unary[idx];
                    acc[i][j][r] = (s < len) ? x : 0.f;
                }
            }

        if (it == 3) {
            #pragma unroll
            for (int i = 0; i < 2; ++i)
                #pragma unroll
                for (int j = 0; j < 4; ++j) {
                    int n = wn + (j << 4) + cn;
                    #pragma unroll
                    for (int r = 0; r < 4; ++r) {
                        int s = s0 + wm + (i << 4) + (quad << 2) + r;
                        out[((long)((b << 10) + s)) * 256 + n] = acc[i][j][r];
                    }
                }
            return;
        }

        // ---- fused row softmax over 256 cols
        #pragma unroll
        for (int i = 0; i < 2; ++i)
            #pragma unroll
            for (int r = 0; r < 4; ++r) {
                float m4 = fmaxf(fmaxf(acc[i][0][r], acc[i][1][r]),
                                 fmaxf(acc[i][2][r], acc[i][3][r]));
                m4 = fmaxf(m4, __shfl_xor(m4, 1));
                m4 = fmaxf(m4, __shfl_xor(m4, 2));
                m4 = fmaxf(m4, __shfl_xor(m4, 4));
                m4 = fmaxf(m4, __shfl_xor(m4, 8));
                if (cn == 0)
                    redA[(nslice << 6) + wm + (i << 4) + (quad << 2) + r] = m4;
            }
        __syncthreads();
        float M[2][4];
        #pragma unroll
        for (int i = 0; i < 2; ++i)
            #pragma unroll
            for (int r = 0; r < 4; ++r) {
                int row = wm + (i << 4) + (quad << 2) + r;
                M[i][r] = fmaxf(fmaxf(redA[row], redA[64 + row]),
                                fmaxf(redA[128 + row], redA[192 + row]));
            }
        #pragma unroll
        for (int i = 0; i < 2; ++i)
            #pragma unroll
            for (int r = 0; r < 4; ++r) {
                float s4 = 0.f;
                #pragma unroll
                for (int j = 0; j < 4; ++j) {
                    float e = __expf(acc[i][j][r] - M[i][r]);
                    acc[i][j][r] = e;
                    s4 += e;
                }
                s4 += __shfl_xor(s4, 1);
                s4 += __shfl_xor(s4, 2);
                s4 += __shfl_xor(s4, 4);
                s4 += __shfl_xor(s4, 8);
                if (cn == 0)
                    redB[(nslice << 6) + wm + (i << 4) + (quad << 2) + r] = s4;
            }
        __syncthreads();

        // ---- write P_{it+1} back into Ps (swizzled, in place)
        #pragma unroll
        for (int i = 0; i < 2; ++i)
            #pragma unroll
            for (int r = 0; r < 4; ++r) {
                int row = wm + (i << 4) + (quad << 2) + r;
                float inv = 1.0f / (redB[row] + redB[64 + row] +
                                    redB[128 + row] + redB[192 + row]);
                int pr = row + 2;
                #pragma unroll
                for (int j = 0; j < 4; ++j) {
                    int n = wn + (j << 4) + cn;
                    int ch = n >> 3;
                    int slot = (ch & ~7) | ((ch ^ pr) & 7);
                    *((__hip_bfloat16*)((char*)Ps + pr * 512 + slot * 16 + (n & 7) * 2)) =
                        __float2bfloat16(acc[i][j][r] * inv);
                }
            }
        __syncthreads();          // Ps updated before publish reads

        // ---- publish 4 boundary rows (linear layout) + release flag
        if (tid < 128) {
            int r_idx = tid >> 5, ch = tid & 31;
            int pr = (r_idx < 2) ? 2 + r_idx : 62 + r_idx;   // 2,3,64,65
            int slot = (ch & ~7) | ((ch ^ pr) & 7);
            bf16x8 v = *(const bf16x8*)((const char*)Ps + (pr * 32 + slot) * 16);
            *(bf16x8*)(Halo + (((size_t)(it - 1) * 512 + tile) * 4 + r_idx) * 256 + ch * 8) = v;
        }
        __syncthreads();          // all publish stores drained (vmcnt0/wave)
        if (tid == 0) {
            __threadfence();      // release: write back before flag
            atomicExch(Flags + tile, it);
        }
    }
}

extern "C" void kernel_launch(void* const* d_in, const int* in_sizes, int n_in,
                              void* d_out, int out_size, void* d_ws, size_t ws_size,
                              hipStream_t stream) {
    const float* unary  = (const float*)d_in[1];
    const float* trans  = (const float*)d_in[3];
    const float* startT = (const float*)d_in[4];
    const float* endT   = (const float*)d_in[5];
    const int*   lens   = (const int*)d_in[6];

    char* ws = (char*)d_ws;
    __hip_bfloat16* WcTt  = (__hip_bfloat16*)ws;                         // 512 KB
    __hip_bfloat16* Halo  = (__hip_bfloat16*)(ws + ((size_t)1 << 20));   // 2 MB
    int*            Flags = (int*)(ws + ((size_t)4 << 20));              // 2 KB
    float* out = (float*)d_out;

    prep_wct<<<dim3(128), dim3(256), 0, stream>>>(trans, WcTt, Flags);
    mfvi_fused<<<dim3(512), dim3(512), 0, stream>>>(WcTt, unary, lens, startT, endT, Halo, Flags, out);
}

// Round 4
// 400.560 us; speedup vs baseline: 1.2543x; 1.2543x over previous
//
#include <hip/hip_runtime.h>
#include <hip/hip_bf16.h>
#include <cstdint>

// MFVI second-order CRF, B=32 S=1024 T=256 W=2 ITER=3.
// msg = Shift(P) @ Wc, M=32768 N=256 K=1024 (4 shift regions).
// Round 9: revert to 4-dispatch skeleton (round 7; fusion disproven, its
// flag-spin cost 330us vs ~120us total kernel time). New iter structure:
//  - BARRIER-FREE K-loop. B (WcT 512KB) is L2/L1-resident and block-shared:
//    load B fragments per-lane from global (4x global_load_dwordx4/step,
//    immediate offsets off 4 base pointers). No Bs LDS, no DMA, no per-step
//    barrier, no vmcnt(0) drains -- removes the m233 stage-drain stall class.
//  - Ps (A) in LDS, staged once in prologue (iter1: in-LDS softmax of unary;
//    iters 2/3: global_load_lds DMA), read-only afterwards. One barrier total
//    before the K-loop.
//  - LDS 37KB/block; launch_bounds(512,2) (grid 512 = 2 blocks/CU resident).
//
// ws: Pa bf16 [32][1028][256] @0 | Pb @32MB | WcT bf16 [256][1024] @64MB

typedef __attribute__((ext_vector_type(4))) float f32x4;
typedef __attribute__((ext_vector_type(8))) short bf16x8;

__device__ __forceinline__ void load_lds16(const void* g, void* l) {
    __builtin_amdgcn_global_load_lds(
        (const __attribute__((address_space(1))) void*)g,
        (__attribute__((address_space(3))) void*)l, 16, 0, 0);
}

// ---------------- prep: plain WcT build + guard rows ------------------------
// WcT[n][k] bf16, n-major [256][1024]. k = region*256 + kk:
//   region 0/1: left msg  W_j[kk][n] (j=1/2); region 2/3: right msg W_j[n][kk].
__global__ __launch_bounds__(256) void prep_wct(
    const float* __restrict__ trans,
    __hip_bfloat16* __restrict__ Pa, __hip_bfloat16* __restrict__ Pb,
    __hip_bfloat16* __restrict__ WcT)
{
    int idx = blockIdx.x * 256 + threadIdx.x;
    if (idx < 32768) {
        int n = idx >> 7, c = idx & 127;
        union { bf16x8 v; __hip_bfloat16 h[8]; } o;
        #pragma unroll
        for (int e = 0; e < 8; ++e) {
            int k = c * 8 + e;
            int r = k >> 8, kk = k & 255;
            float v;
            if (r == 0)      v = trans[kk * 256 + n];
            else if (r == 1) v = trans[65536 + kk * 256 + n];
            else if (r == 2) v = trans[n * 256 + kk];
            else             v = trans[65536 + n * 256 + kk];
            o.h[e] = __float2bfloat16(v);
        }
        ((bf16x8*)WcT)[idx] = o.v;
    } else if (idx < 40960) {
        // zero guard rows (0,1,1026,1027) of Pa and Pb, 16B chunks
        int g = idx - 32768;
        __hip_bfloat16* P = (g & 4096) ? Pb : Pa;
        int rem = g & 4095;
        int b = rem >> 7, wr = (rem >> 5) & 3, ch = rem & 31;
        int row = b * 1028 + ((wr < 2) ? wr : 1024 + wr);
        bf16x8 z = {};
        *(bf16x8*)(P + row * 256 + ch * 8) = z;
    }
}

// ---------------- iteration kernel -----------------------------------------
// Block: 512 threads = 8 waves. M-tile 64 x N 256. Wave w: rows (w>>2)*32..+31,
// cols (w&3)*64..+63. Ps (A, 68x256 swizzled) staged once; B read per-lane
// from global WcT (L1/L2-hot) inside the barrier-free K-loop.
__global__ __launch_bounds__(512, 2) void mfvi_iter_k(
    const __hip_bfloat16* __restrict__ Pin,   // [32][1028][256] padded
    const __hip_bfloat16* __restrict__ WcT,   // [256][1024]
    const float* __restrict__ unary, const int* __restrict__ lengths,
    const float* __restrict__ startT, const float* __restrict__ endT,
    __hip_bfloat16* __restrict__ Pout, float* __restrict__ out,
    int first_it, int final_it)
{
    __shared__ __hip_bfloat16 Ps[68 * 256];       // 34816 B
    __shared__ float redA[256];                   // [nslice][row]
    __shared__ float redB[256];

    int tid = threadIdx.x;
    int lane = tid & 63, w = tid >> 6;
    int cn = lane & 15, quad = lane >> 4;
    int wm = (w >> 2) * 32, wn = (w & 3) * 64;
    int nslice = w & 3;
    int tile = blockIdx.x;
    int b = tile >> 4, s0 = (tile & 15) << 6;
    int len = lengths[b];

    if (first_it) {
        // ---- prologue: P row r (padded 0..67) = softmax(masked unary row
        // s0+r-2), bf16 into swizzled Ps. (validated round-7 path)
        for (int q = 0; q < 9; ++q) {
            int r = w + q * 8;
            if (r >= 68) break;
            int s = s0 + r - 2;
            int ch = lane >> 1;
            int slot = (ch & ~7) | ((ch ^ r) & 7);
            char* dst = (char*)Ps + r * 512 + slot * 16 + (lane & 1) * 8;
            if (s >= 0 && s < 1024) {
                float mval = (s < len) ? 1.f : 0.f;
                float4 x = *((const float4*)(unary + ((size_t)((b << 10) + s)) * 256 + lane * 4));
                x.x *= mval; x.y *= mval; x.z *= mval; x.w *= mval;
                float mx = fmaxf(fmaxf(x.x, x.y), fmaxf(x.z, x.w));
                #pragma unroll
                for (int o = 32; o; o >>= 1) mx = fmaxf(mx, __shfl_xor(mx, o));
                float ea = __expf(x.x - mx), eb = __expf(x.y - mx);
                float ec = __expf(x.z - mx), ed = __expf(x.w - mx);
                float sum = ea + eb + ec + ed;
                #pragma unroll
                for (int o = 32; o; o >>= 1) sum += __shfl_xor(sum, o);
                float inv = 1.0f / sum;
                union { ushort4 u; __hip_bfloat16 h[4]; } o4;
                o4.h[0] = __float2bfloat16(ea * inv);
                o4.h[1] = __float2bfloat16(eb * inv);
                o4.h[2] = __float2bfloat16(ec * inv);
                o4.h[3] = __float2bfloat16(ed * inv);
                *((ushort4*)dst) = o4.u;
            } else {
                ushort4 z = {0, 0, 0, 0};
                *((ushort4*)dst) = z;
            }
        }
    } else {
        // ---- stage Ps via DMA: rows s0-2..s0+65 (padded 0..67), 256 cols.
        // LDS slot c=row*32+ch holds global chunk (ch&~7)|((ch^row)&7).
        const char* Pbase = (const char*)(Pin + ((size_t)b * 1028 + s0) * 256);
        #pragma unroll
        for (int t = 0; t < 5; ++t) {
            int c = t * 512 + tid;
            if (t < 4 || tid < 128) {
                int row = c >> 5, ch = c & 31;
                int gch = (ch & ~7) | ((ch ^ row) & 7);
                load_lds16(Pbase + row * 512 + gch * 16, (char*)Ps + c * 16);
            }
        }
    }
    __syncthreads();          // the ONLY pre-epilogue barrier

    // ---- B base pointers: lane reads WcT row n = wn+j*16+cn, k-chunk quad.
    // Per step (region,q): offset = region*512 + q*64 bytes (imm-foldable).
    const char* Bb[4];
    #pragma unroll
    for (int j = 0; j < 4; ++j)
        Bb[j] = (const char*)WcT + (wn + (j << 4) + cn) * 2048 + quad * 16;

    f32x4 acc[2][4] = {};

    // ---- barrier-free K-loop: 4 regions x 8 steps of K=32.
    #pragma unroll
    for (int region = 0; region < 4; ++region) {
        int delta = (region == 0) ? -1 : (region == 1) ? -2
                  : (region == 2) ?  1 : 2;
        int r0 = wm + cn + delta + 2;             // A row, i=0 (i=1: +16)
        #pragma unroll
        for (int q = 0; q < 8; ++q) {
            int gcb = q * 4 + quad;
            bf16x8 af[2], bfv[4];
            #pragma unroll
            for (int i = 0; i < 2; ++i) {
                int r = r0 + (i << 4);
                int slot = (gcb & ~7) | ((gcb ^ r) & 7);
                af[i] = *(const bf16x8*)((const char*)Ps + r * 512 + slot * 16);
            }
            #pragma unroll
            for (int j = 0; j < 4; ++j)
                bfv[j] = *(const bf16x8*)(Bb[j] + region * 512 + q * 64);
            #pragma unroll
            for (int i = 0; i < 2; ++i)
                #pragma unroll
                for (int j = 0; j < 4; ++j)
                    acc[i][j] = __builtin_amdgcn_mfma_f32_16x16x32_bf16(
                        af[i], bfv[j], acc[i][j], 0, 0, 0);
        }
    }

    // ---- boundary + unary + mask. C/D: col=lane&15, row=quad*4+reg
    #pragma unroll
    for (int i = 0; i < 2; ++i)
        #pragma unroll
        for (int j = 0; j < 4; ++j) {
            int n = wn + (j << 4) + cn;
            #pragma unroll
            for (int r = 0; r < 4; ++r) {
                int s = s0 + wm + (i << 4) + (quad << 2) + r;
                float x = acc[i][j][r];
                if (s == 0)       x += startT[n];
                if (s == 1)       x += startT[256 + n];
                if (s == len - 1) x += endT[n];
                if (s == len - 2) x += endT[256 + n];
                long idx = ((long)((b << 10) + s)) * 256 + n;
                x += unary[idx];
                acc[i][j][r] = (s < len) ? x : 0.f;
            }
        }

    if (final_it) {
        #pragma unroll
        for (int i = 0; i < 2; ++i)
            #pragma unroll
            for (int j = 0; j < 4; ++j) {
                int n = wn + (j << 4) + cn;
                #pragma unroll
                for (int r = 0; r < 4; ++r) {
                    int s = s0 + wm + (i << 4) + (quad << 2) + r;
                    out[((long)((b << 10) + s)) * 256 + n] = acc[i][j][r];
                }
            }
        return;
    }

    // ---- fused row softmax over 256 cols (quad shfl-reduce + LDS combine)
    #pragma unroll
    for (int i = 0; i < 2; ++i)
        #pragma unroll
        for (int r = 0; r < 4; ++r) {
            float m4 = fmaxf(fmaxf(acc[i][0][r], acc[i][1][r]),
                             fmaxf(acc[i][2][r], acc[i][3][r]));
            m4 = fmaxf(m4, __shfl_xor(m4, 1));
            m4 = fmaxf(m4, __shfl_xor(m4, 2));
            m4 = fmaxf(m4, __shfl_xor(m4, 4));
            m4 = fmaxf(m4, __shfl_xor(m4, 8));
            if (cn == 0)
                redA[(nslice << 6) + wm + (i << 4) + (quad << 2) + r] = m4;
        }
    __syncthreads();
    float M[2][4];
    #pragma unroll
    for (int i = 0; i < 2; ++i)
        #pragma unroll
        for (int r = 0; r < 4; ++r) {
            int row = wm + (i << 4) + (quad << 2) + r;
            M[i][r] = fmaxf(fmaxf(redA[row], redA[64 + row]),
                            fmaxf(redA[128 + row], redA[192 + row]));
        }
    #pragma unroll
    for (int i = 0; i < 2; ++i)
        #pragma unroll
        for (int r = 0; r < 4; ++r) {
            float s4 = 0.f;
            #pragma unroll
            for (int j = 0; j < 4; ++j) {
                float e = __expf(acc[i][j][r] - M[i][r]);
                acc[i][j][r] = e;
                s4 += e;
            }
            s4 += __shfl_xor(s4, 1);
            s4 += __shfl_xor(s4, 2);
            s4 += __shfl_xor(s4, 4);
            s4 += __shfl_xor(s4, 8);
            if (cn == 0)
                redB[(nslice << 6) + wm + (i << 4) + (quad << 2) + r] = s4;
        }
    __syncthreads();
    #pragma unroll
    for (int i = 0; i < 2; ++i)
        #pragma unroll
        for (int r = 0; r < 4; ++r) {
            int row = wm + (i << 4) + (quad << 2) + r;
            float inv = 1.0f / (redB[row] + redB[64 + row] +
                                redB[128 + row] + redB[192 + row]);
            int s = s0 + row;
            #pragma unroll
            for (int j = 0; j < 4; ++j) {
                int n = wn + (j << 4) + cn;
                Pout[((size_t)b * 1028 + 2 + s) * 256 + n] =
                    __float2bfloat16(acc[i][j][r] * inv);
            }
        }
}

extern "C" void kernel_launch(void* const* d_in, const int* in_sizes, int n_in,
                              void* d_out, int out_size, void* d_ws, size_t ws_size,
                              hipStream_t stream) {
    const float* unary  = (const float*)d_in[1];
    const float* trans  = (const float*)d_in[3];
    const float* startT = (const float*)d_in[4];
    const float* endT   = (const float*)d_in[5];
    const int*   lens   = (const int*)d_in[6];

    char* ws = (char*)d_ws;
    __hip_bfloat16* Pa  = (__hip_bfloat16*)ws;                          // 16.8 MB
    __hip_bfloat16* Pb  = (__hip_bfloat16*)(ws + ((size_t)32 << 20));   // 16.8 MB
    __hip_bfloat16* WcT = (__hip_bfloat16*)(ws + ((size_t)64 << 20));   // 512 KB
    float* out = (float*)d_out;

    prep_wct<<<dim3(160), dim3(256), 0, stream>>>(trans, Pa, Pb, WcT);
    mfvi_iter_k<<<dim3(512), dim3(512), 0, stream>>>(Pa, WcT, unary, lens, startT, endT, Pb, nullptr, 1, 0);
    mfvi_iter_k<<<dim3(512), dim3(512), 0, stream>>>(Pb, WcT, unary, lens, startT, endT, Pa, nullptr, 0, 0);
    mfvi_iter_k<<<dim3(512), dim3(512), 0, stream>>>(Pa, WcT, unary, lens, startT, endT, nullptr, out, 0, 1);
}

// Round 5
// 278.690 us; speedup vs baseline: 1.8028x; 1.4373x over previous
//
#include <hip/hip_runtime.h>
#include <hip/hip_bf16.h>
#include <cstdint>

// MFVI second-order CRF, B=32 S=1024 T=256 W=2 ITER=3.
// msg = Shift(P) @ Wc, M=32768 N=256 K=1024 (4 shift regions).
// Round 10: round-7 structure (Bs LDS dbuf + tiled pre-swizzled WcTt;
// 48us/iter) with the m201/m218 counted-vmcnt schedule replacing the
// 32 full-drain __syncthreads:
//   step p: vmcnt(2) -> s_barrier -> ds_read (2 af + 4 bfv) -> lgkmcnt(0)
//           -> s_barrier -> issue stage(p+2) -> setprio(1) 16xMFMA setprio(0)
// Next tile's 2 DMA loads ride across barriers (never drained to 0 in-loop).
// Round-9's barrier-free global-B gather (85us/iter, MfmaUtil 7.5%,
// latency-bound 16-segment loads) is reverted.
//
// ws: Pa bf16 [32][1028][256] @0 | Pb @32MB | WcTt bf16 [32][1024]x16B @64MB

typedef __attribute__((ext_vector_type(4))) float f32x4;
typedef __attribute__((ext_vector_type(8))) short bf16x8;

__device__ __forceinline__ void load_lds16(const void* g, void* l) {
    __builtin_amdgcn_global_load_lds(
        (const __attribute__((address_space(1))) void*)g,
        (__attribute__((address_space(3))) void*)l, 16, 0, 0);
}

// ---------------- prep: tiled+pre-swizzled WcT build + guard rows -----------
// WcTt chunk (p, sl): sl = n*4 + cs holds global k-chunk gk = p*4 +
// (cs ^ ((n>>1)&3)) of logical WcT row n (matches K-loop B-read involution).
__global__ __launch_bounds__(256) void prep_wct(
    const float* __restrict__ trans,
    __hip_bfloat16* __restrict__ Pa, __hip_bfloat16* __restrict__ Pb,
    __hip_bfloat16* __restrict__ WcTt)
{
    int idx = blockIdx.x * 256 + threadIdx.x;
    if (idx < 32768) {
        int p = idx >> 10, sl = idx & 1023;
        int n = sl >> 2, cs = sl & 3;
        int gk = p * 4 + (cs ^ ((n >> 1) & 3));
        union { bf16x8 v; __hip_bfloat16 h[8]; } o;
        #pragma unroll
        for (int e = 0; e < 8; ++e) {
            int k = gk * 8 + e;
            int r = k >> 8, kk = k & 255;
            float v;
            if (r == 0)      v = trans[kk * 256 + n];
            else if (r == 1) v = trans[65536 + kk * 256 + n];
            else if (r == 2) v = trans[n * 256 + kk];
            else             v = trans[65536 + n * 256 + kk];
            o.h[e] = __float2bfloat16(v);
        }
        ((bf16x8*)WcTt)[idx] = o.v;
    } else if (idx < 40960) {
        // zero guard rows (0,1,1026,1027) of Pa and Pb, 16B chunks
        int g = idx - 32768;
        __hip_bfloat16* P = (g & 4096) ? Pb : Pa;
        int rem = g & 4095;
        int b = rem >> 7, wr = (rem >> 5) & 3, ch = rem & 31;
        int row = b * 1028 + ((wr < 2) ? wr : 1024 + wr);
        bf16x8 z = {};
        *(bf16x8*)(P + row * 256 + ch * 8) = z;
    }
}

// ---------------- iteration kernel -----------------------------------------
// Block: 512 threads = 8 waves. M-tile 64 x N 256. Wave w: rows (w>>2)*32..+31,
// cols (w&3)*64..+63. Ps (A, 68x256 swizzled) staged once; Bs double-buffered
// with counted-vmcnt pipeline.
__global__ __launch_bounds__(512, 4) void mfvi_iter_k(
    const __hip_bfloat16* __restrict__ Pin,   // [32][1028][256] padded
    const __hip_bfloat16* __restrict__ WcTt,  // [32][1024] x 16B tiles
    const float* __restrict__ unary, const int* __restrict__ lengths,
    const float* __restrict__ startT, const float* __restrict__ endT,
    __hip_bfloat16* __restrict__ Pout, float* __restrict__ out,
    int first_it, int final_it)
{
    __shared__ __hip_bfloat16 Ps[68 * 256];       // 34816 B
    __shared__ __hip_bfloat16 Bs[2 * 256 * 32];   // 2 x 16384 B
    __shared__ float redA[256];                   // [nslice][row]
    __shared__ float redB[256];                   // total 69632 -> 2 blk/CU

    int tid = threadIdx.x;
    int lane = tid & 63, w = tid >> 6;
    int cn = lane & 15, quad = lane >> 4;
    int wm = (w >> 2) * 32, wn = (w & 3) * 64;
    int nslice = w & 3;
    int tile = blockIdx.x;
    int b = tile >> 4, s0 = (tile & 15) << 6;
    int len = lengths[b];

    if (first_it) {
        // ---- prologue: P row r (padded 0..67) = softmax(masked unary row
        // s0+r-2), bf16 into swizzled Ps. (validated round-7 path)
        for (int q = 0; q < 9; ++q) {
            int r = w + q * 8;
            if (r >= 68) break;
            int s = s0 + r - 2;
            int ch = lane >> 1;
            int slot = (ch & ~7) | ((ch ^ r) & 7);
            char* dst = (char*)Ps + r * 512 + slot * 16 + (lane & 1) * 8;
            if (s >= 0 && s < 1024) {
                float mval = (s < len) ? 1.f : 0.f;
                float4 x = *((const float4*)(unary + ((size_t)((b << 10) + s)) * 256 + lane * 4));
                x.x *= mval; x.y *= mval; x.z *= mval; x.w *= mval;
                float mx = fmaxf(fmaxf(x.x, x.y), fmaxf(x.z, x.w));
                #pragma unroll
                for (int o = 32; o; o >>= 1) mx = fmaxf(mx, __shfl_xor(mx, o));
                float ea = __expf(x.x - mx), eb = __expf(x.y - mx);
                float ec = __expf(x.z - mx), ed = __expf(x.w - mx);
                float sum = ea + eb + ec + ed;
                #pragma unroll
                for (int o = 32; o; o >>= 1) sum += __shfl_xor(sum, o);
                float inv = 1.0f / sum;
                union { ushort4 u; __hip_bfloat16 h[4]; } o4;
                o4.h[0] = __float2bfloat16(ea * inv);
                o4.h[1] = __float2bfloat16(eb * inv);
                o4.h[2] = __float2bfloat16(ec * inv);
                o4.h[3] = __float2bfloat16(ed * inv);
                *((ushort4*)dst) = o4.u;
            } else {
                ushort4 z = {0, 0, 0, 0};
                *((ushort4*)dst) = z;
            }
        }
    } else {
        // ---- stage Ps via DMA: rows s0-2..s0+65 (padded 0..67), 256 cols.
        // LDS slot c=row*32+ch holds global chunk (ch&~7)|((ch^row)&7).
        const char* Pbase = (const char*)(Pin + ((size_t)b * 1028 + s0) * 256);
        #pragma unroll
        for (int t = 0; t < 5; ++t) {
            int c = t * 512 + tid;
            if (t < 4 || tid < 128) {
                int row = c >> 5, ch = c & 31;
                int gch = (ch & ~7) | ((ch ^ row) & 7);
                load_lds16(Pbase + row * 512 + gch * 16, (char*)Ps + c * 16);
            }
        }
    }
    __syncthreads();          // drains prologue (Ps writes / Ps DMA)

    // Bs stage for K-step p into buffer bb: linear coalesced 16KB DMA of the
    // pre-swizzled tile (2 chunks/thread; per-wave dest = base + lane*16).
    auto stageB = [&](int bb, int p) {
        #pragma unroll
        for (int c = 0; c < 2; ++c) {
            int sl = c * 512 + tid;
            load_lds16((const char*)WcTt + p * 16384 + sl * 16,
                       (char*)Bs + bb * 16384 + sl * 16);
        }
    };

    stageB(0, 0);
    stageB(1, 1);             // 4 loads/thread in flight entering the loop

    f32x4 acc[2][4] = {};

// ---- counted-vmcnt K-step. VMC is a literal; DMA never drained to 0
// in-loop. Reads of Bs[p&1] complete (lgkmcnt0 + barrier) before the
// overwrite stage(p+2) -> Bs[p&1] is issued; MFMA overlaps that DMA.
#define K_STEP(P, VMC, DOSTAGE) do {                                         \
    asm volatile("s_waitcnt vmcnt(" #VMC ")" ::: "memory");                  \
    __builtin_amdgcn_s_barrier();                                            \
    int region = (P) >> 3;                                                   \
    int delta = (region == 0) ? -1 : (region == 1) ? -2                      \
              : (region == 2) ?  1 : 2;                                      \
    int gcb = ((P) & 7) * 4 + quad;                                          \
    bf16x8 af[2], bfv[4];                                                    \
    _Pragma("unroll")                                                        \
    for (int i = 0; i < 2; ++i) {                                            \
        int r = wm + (i << 4) + cn + delta + 2;                              \
        int slot = (gcb & ~7) | ((gcb ^ r) & 7);                             \
        af[i] = *(const bf16x8*)((const char*)Ps + r * 512 + slot * 16);     \
    }                                                                        \
    _Pragma("unroll")                                                        \
    for (int j = 0; j < 4; ++j) {                                            \
        int n = wn + (j << 4) + cn;                                          \
        int cs = quad ^ ((n >> 1) & 3);                                      \
        bfv[j] = *(const bf16x8*)((const char*)Bs + ((P) & 1) * 16384        \
                                  + n * 64 + cs * 16);                       \
    }                                                                        \
    asm volatile("s_waitcnt lgkmcnt(0)" ::: "memory");                       \
    __builtin_amdgcn_s_barrier();                                            \
    if (DOSTAGE) stageB(((P) & 1), (P) + 2);                                 \
    __builtin_amdgcn_s_setprio(1);                                           \
    _Pragma("unroll")                                                        \
    for (int i = 0; i < 2; ++i)                                              \
        _Pragma("unroll")                                                    \
        for (int j = 0; j < 4; ++j)                                          \
            acc[i][j] = __builtin_amdgcn_mfma_f32_16x16x32_bf16(             \
                af[i], bfv[j], acc[i][j], 0, 0, 0);                          \
    __builtin_amdgcn_s_setprio(0);                                           \
} while (0)

    #pragma unroll
    for (int p = 0; p < 30; ++p) K_STEP(p, 2, true);
    K_STEP(30, 2, false);
    K_STEP(31, 0, false);
#undef K_STEP

    // ---- boundary + unary + mask. C/D: col=lane&15, row=quad*4+reg
    #pragma unroll
    for (int i = 0; i < 2; ++i)
        #pragma unroll
        for (int j = 0; j < 4; ++j) {
            int n = wn + (j << 4) + cn;
            #pragma unroll
            for (int r = 0; r < 4; ++r) {
                int s = s0 + wm + (i << 4) + (quad << 2) + r;
                float x = acc[i][j][r];
                if (s == 0)       x += startT[n];
                if (s == 1)       x += startT[256 + n];
                if (s == len - 1) x += endT[n];
                if (s == len - 2) x += endT[256 + n];
                long idx = ((long)((b << 10) + s)) * 256 + n;
                x += unary[idx];
                acc[i][j][r] = (s < len) ? x : 0.f;
            }
        }

    if (final_it) {
        #pragma unroll
        for (int i = 0; i < 2; ++i)
            #pragma unroll
            for (int j = 0; j < 4; ++j) {
                int n = wn + (j << 4) + cn;
                #pragma unroll
                for (int r = 0; r < 4; ++r) {
                    int s = s0 + wm + (i << 4) + (quad << 2) + r;
                    out[((long)((b << 10) + s)) * 256 + n] = acc[i][j][r];
                }
            }
        return;
    }

    // ---- fused row softmax over 256 cols (quad shfl-reduce + LDS combine)
    #pragma unroll
    for (int i = 0; i < 2; ++i)
        #pragma unroll
        for (int r = 0; r < 4; ++r) {
            float m4 = fmaxf(fmaxf(acc[i][0][r], acc[i][1][r]),
                             fmaxf(acc[i][2][r], acc[i][3][r]));
            m4 = fmaxf(m4, __shfl_xor(m4, 1));
            m4 = fmaxf(m4, __shfl_xor(m4, 2));
            m4 = fmaxf(m4, __shfl_xor(m4, 4));
            m4 = fmaxf(m4, __shfl_xor(m4, 8));
            if (cn == 0)
                redA[(nslice << 6) + wm + (i << 4) + (quad << 2) + r] = m4;
        }
    __syncthreads();
    float M[2][4];
    #pragma unroll
    for (int i = 0; i < 2; ++i)
        #pragma unroll
        for (int r = 0; r < 4; ++r) {
            int row = wm + (i << 4) + (quad << 2) + r;
            M[i][r] = fmaxf(fmaxf(redA[row], redA[64 + row]),
                            fmaxf(redA[128 + row], redA[192 + row]));
        }
    #pragma unroll
    for (int i = 0; i < 2; ++i)
        #pragma unroll
        for (int r = 0; r < 4; ++r) {
            float s4 = 0.f;
            #pragma unroll
            for (int j = 0; j < 4; ++j) {
                float e = __expf(acc[i][j][r] - M[i][r]);
                acc[i][j][r] = e;
                s4 += e;
            }
            s4 += __shfl_xor(s4, 1);
            s4 += __shfl_xor(s4, 2);
            s4 += __shfl_xor(s4, 4);
            s4 += __shfl_xor(s4, 8);
            if (cn == 0)
                redB[(nslice << 6) + wm + (i << 4) + (quad << 2) + r] = s4;
        }
    __syncthreads();
    #pragma unroll
    for (int i = 0; i < 2; ++i)
        #pragma unroll
        for (int r = 0; r < 4; ++r) {
            int row = wm + (i << 4) + (quad << 2) + r;
            float inv = 1.0f / (redB[row] + redB[64 + row] +
                                redB[128 + row] + redB[192 + row]);
            int s = s0 + row;
            #pragma unroll
            for (int j = 0; j < 4; ++j) {
                int n = wn + (j << 4) + cn;
                Pout[((size_t)b * 1028 + 2 + s) * 256 + n] =
                    __float2bfloat16(acc[i][j][r] * inv);
            }
        }
}

extern "C" void kernel_launch(void* const* d_in, const int* in_sizes, int n_in,
                              void* d_out, int out_size, void* d_ws, size_t ws_size,
                              hipStream_t stream) {
    const float* unary  = (const float*)d_in[1];
    const float* trans  = (const float*)d_in[3];
    const float* startT = (const float*)d_in[4];
    const float* endT   = (const float*)d_in[5];
    const int*   lens   = (const int*)d_in[6];

    char* ws = (char*)d_ws;
    __hip_bfloat16* Pa   = (__hip_bfloat16*)ws;                          // 16.8 MB
    __hip_bfloat16* Pb   = (__hip_bfloat16*)(ws + ((size_t)32 << 20));   // 16.8 MB
    __hip_bfloat16* WcTt = (__hip_bfloat16*)(ws + ((size_t)64 << 20));   // 512 KB
    float* out = (float*)d_out;

    prep_wct<<<dim3(160), dim3(256), 0, stream>>>(trans, Pa, Pb, WcTt);
    mfvi_iter_k<<<dim3(512), dim3(512), 0, stream>>>(Pa, WcTt, unary, lens, startT, endT, Pb, nullptr, 1, 0);
    mfvi_iter_k<<<dim3(512), dim3(512), 0, stream>>>(Pb, WcTt, unary, lens, startT, endT, Pa, nullptr, 0, 0);
    mfvi_iter_k<<<dim3(512), dim3(512), 0, stream>>>(Pa, WcTt, unary, lens, startT, endT, nullptr, out, 0, 1);
}